// Round 10
// baseline (201.619 us; speedup 1.0000x reference)
//
#include <hip/hip_runtime.h>
#include <math.h>

// GCN 2-layer forward on MI355X — round 24:
//  * base = round 23 (199.5us best).
//  * k_gemm_rank LDS ELIMINATED: the 32KB W1 staging capped co-residency at
//    5 blocks/CU (OccupancyPercent 37) for ALL blocks — including the 586
//    latency-bound edge-atomic blocks that never touch LDS. W1 frag images
//    are 32KB, L2-resident, broadcast: gemm1 now reads hi/lo fragments
//    per-MFMA from global (coalesced 1KB/wave, L2-hot). Kernel LDS -> 0,
//    occupancy now VGPR-capped (~10 waves/SIMD).
//  Dispatches: prep, gemm_rank, scan1, fill(+pad), agg_gemm, agg2 (6).
#define CH   128
#define CH4  32
#define TPB  256
#define SCANB 1024
#define WIMG 16384       // shorts per (layer,colh) fragment image (32 KB)
#define NREP 8
#define FIXS 1048576.0f  // 2^20 fixed-point scale for packed degsum

typedef __attribute__((ext_vector_type(8))) short short8;   // 8 bf16 (4 VGPRs)
typedef __attribute__((ext_vector_type(4))) float floatx4;  // MFMA acc
typedef __attribute__((ext_vector_type(8))) float float8;
typedef unsigned long long u64;

static __device__ __forceinline__ unsigned short f2bf(float f) {
    unsigned u = __float_as_uint(f);
    return (unsigned short)((u + 0x7fffu + ((u >> 16) & 1u)) >> 16);
}
static __device__ __forceinline__ float bf2f(unsigned short s) {
    return __uint_as_float(((unsigned)s) << 16);
}
static __device__ __forceinline__ float8 bf8_to_f8(short8 u) {
    float8 f;
    #pragma unroll
    for (int i = 0; i < 8; ++i) f[i] = bf2f((unsigned short)u[i]);
    return f;
}

// ---------------------------------------------------------------------------
// k_prep: blocks [0,nbPrep): split W1,W2 into bf16 hi/lo fragment images;
// blocks [nbPrep,..): zero packed counts_rep (u64) + done.
// ---------------------------------------------------------------------------
__global__ void k_prep(const float* __restrict__ W1, const float* __restrict__ W2,
                       short* __restrict__ Wsplit, float4* __restrict__ zbase,
                       int nzero4, int nbPrep) {
    int bx = blockIdx.x;
    if (bx >= nbPrep) {
        int i = (bx - nbPrep) * TPB + threadIdx.x;
        if (i < nzero4) zbase[i] = make_float4(0.f, 0.f, 0.f, 0.f);
        return;
    }
    int i = bx * TPB + threadIdx.x;   // over 2*128*128
    if (i >= 2 * CH * CH) return;
    int layer = i >> 14;
    int idx   = i & 16383;
    int k = idx >> 7, c = idx & 127;
    float w = (layer ? W2 : W1)[k * CH + c];
    unsigned short hi = f2bf(w);
    unsigned short lo = f2bf(w - bf2f(hi));
    int colh = c >> 6, nn = c & 63;
    int kt = k >> 5, q = (k & 31) >> 3, j = k & 7;
    int ns = nn >> 4, ln = q * 16 + (nn & 15);
    size_t base = (size_t)(layer * 2 + colh) * WIMG;
    size_t off  = ((size_t)(kt * 4 + ns) * 64 + ln) * 8 + j;
    Wsplit[base + off]        = (short)hi;   // hi: first 16 KB of image
    Wsplit[base + 8192 + off] = (short)lo;   // lo: second 16 KB
}

// ---------------------------------------------------------------------------
// fp32-input MFMA GEMM body (3-term Markidis split), bf16 output. (layer 1)
// W frags read straight from L2-hot global (no LDS -> no occupancy cap).
// A: m=lane&15, k=(lane>>4)*8+j ; B mirrored ; D: col=lane&15, row=(lane>>4)*4+reg
// ---------------------------------------------------------------------------
static __device__ __forceinline__ void gemm_body_f32(
        const float* __restrict__ X, const short* __restrict__ Wfrag,
        unsigned short* __restrict__ H, int n, int tile, int colh, int tid) {
    const int lane = tid & 63;
    const int wv   = tid >> 6;
    const int q    = lane >> 4;
    const int m    = lane & 15;
    const int row0 = tile * 64 + wv * 16;
    if (row0 >= n) return;

    int rrow = row0 + m;
    if (rrow > n - 1) rrow = n - 1;

    const float4* xr = (const float4*)(X + (size_t)rrow * CH);
    float4 xa[4][2];
    #pragma unroll
    for (int kt = 0; kt < 4; ++kt) {
        xa[kt][0] = xr[kt * 8 + q * 2 + 0];
        xa[kt][1] = xr[kt * 8 + q * 2 + 1];
    }

    const short8* wf = (const short8*)Wfrag;   // hi: [0,1024), lo: [1024,2048)

    floatx4 acc[4];
    #pragma unroll
    for (int ns = 0; ns < 4; ++ns) acc[ns] = (floatx4){0.f, 0.f, 0.f, 0.f};

    #pragma unroll
    for (int kt = 0; kt < 4; ++kt) {
        float xf[8] = { xa[kt][0].x, xa[kt][0].y, xa[kt][0].z, xa[kt][0].w,
                        xa[kt][1].x, xa[kt][1].y, xa[kt][1].z, xa[kt][1].w };
        short8 ah, al;
        #pragma unroll
        for (int j = 0; j < 8; ++j) {
            float v = xf[j];
            unsigned short h = f2bf(v);
            ah[j] = (short)h;
            al[j] = (short)f2bf(v - bf2f(h));
        }
        #pragma unroll
        for (int ns = 0; ns < 4; ++ns) {
            short8 bh = wf[(kt * 4 + ns) * 64 + lane];
            short8 bl = wf[1024 + (kt * 4 + ns) * 64 + lane];
            acc[ns] = __builtin_amdgcn_mfma_f32_16x16x32_bf16(ah, bh, acc[ns], 0, 0, 0);
            acc[ns] = __builtin_amdgcn_mfma_f32_16x16x32_bf16(al, bh, acc[ns], 0, 0, 0);
            acc[ns] = __builtin_amdgcn_mfma_f32_16x16x32_bf16(ah, bl, acc[ns], 0, 0, 0);
        }
    }

    #pragma unroll
    for (int ns = 0; ns < 4; ++ns) {
        #pragma unroll
        for (int reg = 0; reg < 4; ++reg) {
            int r = row0 + q * 4 + reg;
            if (r < n)
                H[(size_t)r * CH + colh * 64 + ns * 16 + m] = f2bf(acc[ns][reg]);
        }
    }
}

// fused: blocks [0, nbE4): per-edge packed rank+degsum u64 atomic, grid-stride
// x4 (long pole, dispatched first); blocks [nbE4, ...): gemm1 (fp32 x).
// NO LDS in this kernel -> edge blocks are VGPR-capped only.
__global__ __launch_bounds__(TPB, 4)
void k_gemm_rank(const float* __restrict__ X, const short* __restrict__ Wsplit,
                 unsigned short* __restrict__ H, int n,
                 const int* __restrict__ dst, const float* __restrict__ ew,
                 u64* __restrict__ counts_rep, int* __restrict__ rank,
                 int E, int nbE4, int Np) {
    int bx = blockIdx.x;
    if (bx < nbE4) {
        int stride = nbE4 * TPB;
        int e = bx * TPB + threadIdx.x;
        #pragma unroll
        for (int it = 0; it < 4; ++it, e += stride) {
            if (e < E) {
                int d = dst[e];
                if ((unsigned)d < (unsigned)n) {
                    int rep = e & (NREP - 1);
                    u64 pk = (1ull << 40) |
                             (u64)(unsigned)__float2uint_rn(ew[e] * FIXS);
                    u64 old = atomicAdd(&counts_rep[(size_t)rep * Np + d], pk);
                    rank[e] = (int)(old >> 40);
                }
            }
        }
    } else {
        bx -= nbE4;
        int colh = bx & 1;
        gemm_body_f32(X, Wsplit + (size_t)colh * WIMG, H, n, bx >> 1, colh,
                      threadIdx.x);
    }
}

// ---------------------------------------------------------------------------
// scan1 (shfl): unpack 8 packed replicas -> v (true count) + dinv; scan the
// PADDED count vp=(v+7)&~7 for row_start; replica-exclusive offsets; last
// block top-scans padded partials into pp_s.
// ---------------------------------------------------------------------------
__global__ __launch_bounds__(SCANB)
void k_scan1(const u64* __restrict__ counts_rep, int Np,
             int* __restrict__ counts_tot, int* __restrict__ repoff8,
             int* __restrict__ row_start, float* __restrict__ dinv,
             int* __restrict__ partials, int* __restrict__ pp_s,
             int* __restrict__ done, int nb, int n) {
    __shared__ int swt[SCANB / 64];   // 16 wave totals / exclusive offsets
    __shared__ int slastS;
    const int tid  = threadIdx.x;
    const int lane = tid & 63;
    const int wid  = tid >> 6;
    const int gid  = blockIdx.x * SCANB + tid;

    int c[NREP];
    int v = 0;
    u64 wsum = 0;
    #pragma unroll
    for (int r = 0; r < NREP; ++r) {
        u64 pk = (gid < n) ? counts_rep[(size_t)r * Np + gid] : 0ull;
        c[r] = (int)(pk >> 40);
        wsum += pk & ((1ull << 40) - 1);
        v += c[r];
    }
    const int vp = (v + 7) & ~7;            // padded bucket length
    // wave-inclusive scan of padded counts
    int inc = vp;
    #pragma unroll
    for (int off = 1; off < 64; off <<= 1) {
        int t = __shfl_up(inc, off, 64);
        if (lane >= off) inc += t;
    }
    if (lane == 63) swt[wid] = inc;
    __syncthreads();
    if (wid == 0) {
        int wv_ = (lane < SCANB / 64) ? swt[lane] : 0;
        int winc = wv_;
        #pragma unroll
        for (int off = 1; off < SCANB / 64; off <<= 1) {
            int t = __shfl_up(winc, off, 64);
            if (lane >= off) winc += t;
        }
        if (lane < SCANB / 64) swt[lane] = winc - wv_;   // exclusive
    }
    __syncthreads();
    const int myincl = inc + swt[wid];      // block-inclusive padded prefix

    if (gid < n) {
        row_start[gid]  = myincl - vp;      // block-local exclusive (padded)
        counts_tot[gid] = v;                // true count
        dinv[gid] = rsqrtf(1.0f + (float)wsum * (1.0f / FIXS));
        int pre = 0;
        int ro[NREP];
        #pragma unroll
        for (int r = 0; r < NREP; ++r) { ro[r] = pre; pre += c[r]; }
        ((int4*)repoff8)[gid * 2 + 0] = make_int4(ro[0], ro[1], ro[2], ro[3]);
        ((int4*)repoff8)[gid * 2 + 1] = make_int4(ro[4], ro[5], ro[6], ro[7]);
    }
    if (tid == SCANB - 1) {                 // holds the block total
        partials[blockIdx.x] = myincl;
        __threadfence();
        int old = atomicAdd(done, 1);
        slastS = (old == nb - 1);
    }
    __syncthreads();
    if (slastS && tid < 64) {
        int pv = (tid < nb) ? atomicAdd(&partials[tid], 0) : 0;
        int i2 = pv;
        #pragma unroll
        for (int off = 1; off < 64; off <<= 1) {
            int t = __shfl_up(i2, off, 64);
            if ((tid & 63) >= off) i2 += t;
        }
        if (tid < nb) pp_s[tid] = i2 - pv;
    }
}

// fill: blocks [0,nbE): per-edge forward fill via rank (atomic-free);
// blocks [nbE, nbE+nbN): per-node pad writer ({src=0, w=0} to round buckets
// up to a multiple of 8). pp_s is valid here (scan completed).
__global__ void k_fill(const int* __restrict__ src, const int* __restrict__ dst,
                       const float* __restrict__ ew, const int* __restrict__ row_start,
                       const int* __restrict__ pp_s, const int* __restrict__ repoff8,
                       const int* __restrict__ rank, const float* __restrict__ dinv,
                       const int* __restrict__ counts_tot,
                       int2* __restrict__ edges, int E, int n, int nbE) {
    int bx = blockIdx.x;
    if (bx >= nbE) {
        int node = (bx - nbE) * TPB + threadIdx.x;
        if (node >= n) return;
        int v  = counts_tot[node];
        int vp = (v + 7) & ~7;
        if (v == vp) return;
        int base = row_start[node] + pp_s[node >> 10] + v;
        for (int k = 0; k < vp - v; ++k)
            edges[base + k] = make_int2(0, 0);   // w=0 pad, gathers row 0
        return;
    }
    int e = bx * TPB + threadIdx.x;
    if (e >= E) return;
    int s = src[e], d = dst[e];
    if ((unsigned)s >= (unsigned)n || (unsigned)d >= (unsigned)n) return;
    int rep = e & (NREP - 1);
    int base = row_start[d] + pp_s[d >> 10] + repoff8[d * NREP + rep];
    edges[base + rank[e]] = make_int2(s, __float_as_int(ew[e] * dinv[s]));
}

// ---------------------------------------------------------------------------
// aggregate core over UNscaled h (16 lanes/node, short8 loads). Buckets are
// padded to a multiple of 8 -> only full 8-wide batches, no tail.
//   o = di^2 * h[node] + di * sum_e w~_e * h[src_e] + bias
// ---------------------------------------------------------------------------
static __device__ __forceinline__ float8 agg_node8(
        const short8* __restrict__ h8, const int2* __restrict__ edges,
        float di, const float8 b, int node, int tx,
        const int* __restrict__ row_start, const int* __restrict__ pp_s,
        const int* __restrict__ counts) {
    float8 hv = bf8_to_f8(h8[(size_t)node * 16 + tx]);
    float8 acc;
    #pragma unroll
    for (int i = 0; i < 8; ++i) acc[i] = 0.f;

    int j   = row_start[node] + pp_s[node >> 10];
    int end = j + ((counts[node] + 7) & ~7);    // padded length

    for (; j < end; j += 8) {
        int2 e[8];
        #pragma unroll
        for (int i = 0; i < 8; ++i) e[i] = edges[j + i];
        short8 g[8];
        #pragma unroll
        for (int i = 0; i < 8; ++i) g[i] = h8[(size_t)e[i].x * 16 + tx];
        #pragma unroll
        for (int i = 0; i < 8; ++i) {
            float w = __int_as_float(e[i].y);
            float8 gf = bf8_to_f8(g[i]);
            #pragma unroll
            for (int c = 0; c < 8; ++c) acc[c] += gf[c] * w;
        }
    }

    float di2 = di * di;
    float8 o;
    #pragma unroll
    for (int c = 0; c < 8; ++c) o[c] = di2 * hv[c] + di * acc[c] + b[c];
    return o;
}

// ---------------------------------------------------------------------------
// k_agg_gemm: 16 nodes/block (agg1 parallel shape, 3125 blocks).
// Phase 1: one node-slice per thread -> LDS tile (pitch 17 short8, 4.3 KB).
// Phase 2: 16x128 tile @ W2; 4 waves split (colh, ns); 8 MFMAs/wave;
// B-frags from L2-hot global.
// ---------------------------------------------------------------------------
__global__ __launch_bounds__(TPB)
void k_agg_gemm(const unsigned short* __restrict__ h,
                const int* __restrict__ row_start, const int* __restrict__ pp_s,
                const int* __restrict__ counts, const int2* __restrict__ edges,
                const float* __restrict__ dinv, const float* __restrict__ bias,
                const short* __restrict__ W2img,   // Wsplit + 2*WIMG
                unsigned short* __restrict__ h2, int n) {
    __shared__ __align__(16) short8 tile[16 * 17];       // 4.3 KB, pitch 17
    const int tid = threadIdx.x;

    // ---- phase 1: aggregate 16 nodes, one slice per thread ----
    const int bnode0 = (int)blockIdx.x * 16;
    const int tx = tid & 15;
    const int tg = tid >> 4;          // node-local index [0,16)
    const int node = bnode0 + tg;
    float8 b;
    #pragma unroll
    for (int c = 0; c < 8; ++c) b[c] = bias[tx * 8 + c];
    short8 u;
    if (node < n) {
        float8 o = agg_node8((const short8*)h, edges, dinv[node], b, node,
                             tx, row_start, pp_s, counts);
        #pragma unroll
        for (int c = 0; c < 8; ++c) u[c] = (short)f2bf(fmaxf(o[c], 0.f));
    } else {
        #pragma unroll
        for (int c = 0; c < 8; ++c) u[c] = 0;
    }
    tile[tg * 17 + tx] = u;
    __syncthreads();

    // ---- phase 2: 16x128 tile @ 128x128 W2 (B from global, L2-hot) ----
    const int lane = tid & 63;
    const int wv   = tid >> 6;        // 0..3
    const int q    = lane >> 4;
    const int m    = lane & 15;
    const int ch   = wv & 1;
    const int ns0  = (wv >> 1) * 2;

    short8 a[4];
    #pragma unroll
    for (int kt = 0; kt < 4; ++kt)
        a[kt] = tile[m * 17 + kt * 4 + q];

    const short8* w2f = (const short8*)(W2img + (size_t)ch * WIMG);

    floatx4 acc[2];
    #pragma unroll
    for (int i = 0; i < 2; ++i) acc[i] = (floatx4){0.f, 0.f, 0.f, 0.f};

    #pragma unroll
    for (int kt = 0; kt < 4; ++kt) {
        #pragma unroll
        for (int i = 0; i < 2; ++i) {
            short8 bh = w2f[(kt * 4 + ns0 + i) * 64 + lane];
            acc[i] = __builtin_amdgcn_mfma_f32_16x16x32_bf16(a[kt], bh, acc[i],
                                                             0, 0, 0);
        }
    }

    #pragma unroll
    for (int i = 0; i < 2; ++i)
        #pragma unroll
        for (int reg = 0; reg < 4; ++reg) {
            int r = bnode0 + q * 4 + reg;
            if (r < n)
                h2[(size_t)r * CH + ch * 64 + (ns0 + i) * 16 + m] =
                    f2bf(acc[i][reg]);
        }
}

// agg2: out = relu(agg(h2)) in fp32.
__global__ __launch_bounds__(TPB)
void k_aggregate2(const unsigned short* __restrict__ h,
                  const int* __restrict__ row_start, const int* __restrict__ pp_s,
                  const int* __restrict__ counts, const int2* __restrict__ edges,
                  const float* __restrict__ dinv, const float* __restrict__ bias,
                  float* __restrict__ out, int n) {
    int t = blockIdx.x * blockDim.x + threadIdx.x;
    int node = t >> 4;
    if (node >= n) return;
    int tx = t & 15;
    float8 b;
    #pragma unroll
    for (int c = 0; c < 8; ++c) b[c] = bias[tx * 8 + c];
    float8 o = agg_node8((const short8*)h, edges, dinv[node], b, node, tx,
                         row_start, pp_s, counts);
    float4 lo = make_float4(fmaxf(o[0], 0.f), fmaxf(o[1], 0.f),
                            fmaxf(o[2], 0.f), fmaxf(o[3], 0.f));
    float4 hi = make_float4(fmaxf(o[4], 0.f), fmaxf(o[5], 0.f),
                            fmaxf(o[6], 0.f), fmaxf(o[7], 0.f));
    ((float4*)out)[(size_t)node * CH4 + tx * 2 + 0] = lo;
    ((float4*)out)[(size_t)node * CH4 + tx * 2 + 1] = hi;
}

// ---------------------------------------------------------------------------
extern "C" void kernel_launch(void* const* d_in, const int* in_sizes, int n_in,
                              void* d_out, int out_size, void* d_ws, size_t ws_size,
                              hipStream_t stream) {
    const float* x  = (const float*)d_in[0];   // [N,128]
    const int*   ei = (const int*)d_in[1];     // [2,E]
    const float* ew = (const float*)d_in[2];   // [E]
    const float* W1 = (const float*)d_in[3];
    const float* b1 = (const float*)d_in[4];
    const float* W2 = (const float*)d_in[5];
    const float* b2 = (const float*)d_in[6];
    float* out = (float*)d_out;                // [N,128]

    const int N = in_sizes[0] / CH;
    const int E = in_sizes[2];
    const int* src = ei;
    const int* dst = ei + E;

    // workspace layout (16B-aligned)
    size_t Np   = ((size_t)N + 255) & ~(size_t)255;
    size_t Ep   = ((size_t)E + 63) & ~(size_t)63;
    size_t Epad = (size_t)E + 8 * Np;          // padded edge capacity
    float* ws          = (float*)d_ws;
    float* dinv        = ws;                                // Np floats
    unsigned short* h  = (unsigned short*)(dinv + Np);      // N*CH bf16 (gemm1 out)
    unsigned short* h2 = h + (size_t)N * CH;                // N*CH bf16 (gemm2 out)
    // ---- contiguous zero region ----
    u64*   counts_rep  = (u64*)(h2 + (size_t)N * CH);       // NREP*Np u64 (packed)
    int*   done        = (int*)(counts_rep + NREP * Np);    // 64 ints (1 used)
    int    nzero4      = (int)((2 * NREP * Np + 64) / 4);
    // ---- rest ----
    int*  counts_tot   = done + 64;                         // Np ints
    int*  row_start    = counts_tot + Np;                   // Np ints
    int*  repoff8      = row_start + Np;                    // NREP*Np ints
    int*  rank         = repoff8 + NREP * Np;               // Ep ints
    int*  partials     = rank + Ep;                         // 64 ints
    int*  pp_s         = partials + 64;                     // 64 ints
    int2* edges        = (int2*)(pp_s + 64);                // Epad int2
    short* Wsplit      = (short*)(edges + Epad);            // 4*WIMG shorts

    const int nbE    = (E + TPB - 1) / TPB;
    const int nbN    = (N + TPB - 1) / TPB;
    const int nbE4   = (E + TPB * 4 - 1) / (TPB * 4);
    const int nbAgg  = (int)(((size_t)N * 16 + TPB - 1) / TPB);
    const int nbScan = (N + SCANB - 1) / SCANB;     // 49 <= 64
    const int nbGemm = 2 * ((N + 63) / 64);
    const int nbAG   = (N + 15) / 16;               // 16 nodes/block
    const int nbPrep = (2 * CH * CH + TPB - 1) / TPB;
    const int nbZero = (nzero4 + TPB - 1) / TPB;

    // ---- prep: split W + zero counters (fused) ----
    k_prep     <<<nbPrep + nbZero, TPB, 0, stream>>>(W1, W2, Wsplit,
                                                     (float4*)counts_rep,
                                                     nzero4, nbPrep);

    // ---- fused: packed rank+degsum pass (grid-stride x4) | gemm1 ----
    k_gemm_rank<<<nbE4 + nbGemm, TPB, 0, stream>>>(x, Wsplit, h, N, dst, ew,
                                                   counts_rep, rank, E, nbE4,
                                                   (int)Np);
    // ---- CSR finalize (+ dinv), padded buckets ----
    k_scan1    <<<nbScan, SCANB, 0, stream>>>(counts_rep, (int)Np, counts_tot,
                                              repoff8, row_start, dinv,
                                              partials, pp_s, done, nbScan, N);
    // ---- forward fill + pad writer (fused grids) ----
    k_fill     <<<nbE + nbN, TPB, 0, stream>>>(src, dst, ew, row_start, pp_s,
                                               repoff8, rank, dinv, counts_tot,
                                               edges, E, N, nbE);

    // ---- layer 1 aggregate + layer 2 gemm (fused) -> h2 ----
    k_agg_gemm <<<nbAG, TPB, 0, stream>>>(h, row_start, pp_s, counts_tot,
                                          edges, dinv, b1,
                                          Wsplit + 2 * (size_t)WIMG, h2, N);
    // ---- layer 2 aggregate ----
    k_aggregate2<<<nbAgg, TPB, 0, stream>>>(h2, row_start, pp_s, counts_tot,
                                            edges, dinv, b2, out, N);
}

// Round 11
// 199.138 us; speedup vs baseline: 1.0125x; 1.0125x over previous
//
#include <hip/hip_runtime.h>
#include <math.h>

// GCN 2-layer forward on MI355X — round 25:
//  * base = round 23 (199.5us best; round-24 LDS removal reverted).
//  * XCD-LOCAL REPLICAS: rep = HW_REG_XCC_ID (not e&7). Each (rep,node)
//    counter line is only atomically updated from its own XCD -> the line
//    stays in the local L2 (no cross-die ownership migration per atomic).
//    rank[e] = (rep<<28) | slot so k_fill knows which replica counted it.
//  Dispatches: prep, gemm_rank, scan1, fill(+pad), agg_gemm, agg2 (6).
#define CH   128
#define CH4  32
#define TPB  256
#define SCANB 1024
#define WIMG 16384       // shorts per (layer,colh) fragment image (32 KB)
#define NREP 8
#define FIXS 1048576.0f  // 2^20 fixed-point scale for packed degsum

typedef __attribute__((ext_vector_type(8))) short short8;   // 8 bf16 (4 VGPRs)
typedef __attribute__((ext_vector_type(4))) float floatx4;  // MFMA acc
typedef __attribute__((ext_vector_type(8))) float float8;
typedef unsigned long long u64;

static __device__ __forceinline__ unsigned short f2bf(float f) {
    unsigned u = __float_as_uint(f);
    return (unsigned short)((u + 0x7fffu + ((u >> 16) & 1u)) >> 16);
}
static __device__ __forceinline__ float bf2f(unsigned short s) {
    return __uint_as_float(((unsigned)s) << 16);
}
static __device__ __forceinline__ float8 bf8_to_f8(short8 u) {
    float8 f;
    #pragma unroll
    for (int i = 0; i < 8; ++i) f[i] = bf2f((unsigned short)u[i]);
    return f;
}
static __device__ __forceinline__ int xcc_id() {
    int x;
    asm volatile("s_getreg_b32 %0, hwreg(HW_REG_XCC_ID)" : "=s"(x));
    return x & (NREP - 1);
}

// ---------------------------------------------------------------------------
// k_prep: blocks [0,nbPrep): split W1,W2 into bf16 hi/lo fragment images;
// blocks [nbPrep,..): zero packed counts_rep (u64) + done.
// ---------------------------------------------------------------------------
__global__ void k_prep(const float* __restrict__ W1, const float* __restrict__ W2,
                       short* __restrict__ Wsplit, float4* __restrict__ zbase,
                       int nzero4, int nbPrep) {
    int bx = blockIdx.x;
    if (bx >= nbPrep) {
        int i = (bx - nbPrep) * TPB + threadIdx.x;
        if (i < nzero4) zbase[i] = make_float4(0.f, 0.f, 0.f, 0.f);
        return;
    }
    int i = bx * TPB + threadIdx.x;   // over 2*128*128
    if (i >= 2 * CH * CH) return;
    int layer = i >> 14;
    int idx   = i & 16383;
    int k = idx >> 7, c = idx & 127;
    float w = (layer ? W2 : W1)[k * CH + c];
    unsigned short hi = f2bf(w);
    unsigned short lo = f2bf(w - bf2f(hi));
    int colh = c >> 6, nn = c & 63;
    int kt = k >> 5, q = (k & 31) >> 3, j = k & 7;
    int ns = nn >> 4, ln = q * 16 + (nn & 15);
    size_t base = (size_t)(layer * 2 + colh) * WIMG;
    size_t off  = ((size_t)(kt * 4 + ns) * 64 + ln) * 8 + j;
    Wsplit[base + off]        = (short)hi;   // hi: first 16 KB of image
    Wsplit[base + 8192 + off] = (short)lo;   // lo: second 16 KB
}

// ---------------------------------------------------------------------------
// fp32-input MFMA GEMM body (3-term Markidis split), bf16 output. (layer 1)
// A: m=lane&15, k=(lane>>4)*8+j ; B mirrored ; D: col=lane&15, row=(lane>>4)*4+reg
// ---------------------------------------------------------------------------
static __device__ __forceinline__ void gemm_body_f32(
        const float* __restrict__ X, const short* __restrict__ Wfrag,
        unsigned short* __restrict__ H, int n, int tile, int colh, int tid) {
    __shared__ __align__(16) short sW[2][4][4][64][8];   // 32 KB (hi+lo)
    {
        const float4* gsrc = (const float4*)Wfrag;
        float4* ldst = (float4*)sW;
        #pragma unroll
        for (int i = 0; i < 8; ++i)
            ldst[i * TPB + tid] = gsrc[i * TPB + tid];
    }
    __syncthreads();

    const int lane = tid & 63;
    const int wv   = tid >> 6;
    const int q    = lane >> 4;
    const int m    = lane & 15;
    const int row0 = tile * 64 + wv * 16;
    if (row0 >= n) return;

    int rrow = row0 + m;
    if (rrow > n - 1) rrow = n - 1;

    const float4* xr = (const float4*)(X + (size_t)rrow * CH);
    float4 xa[4][2];
    #pragma unroll
    for (int kt = 0; kt < 4; ++kt) {
        xa[kt][0] = xr[kt * 8 + q * 2 + 0];
        xa[kt][1] = xr[kt * 8 + q * 2 + 1];
    }

    floatx4 acc[4];
    #pragma unroll
    for (int ns = 0; ns < 4; ++ns) acc[ns] = (floatx4){0.f, 0.f, 0.f, 0.f};

    #pragma unroll
    for (int kt = 0; kt < 4; ++kt) {
        float xf[8] = { xa[kt][0].x, xa[kt][0].y, xa[kt][0].z, xa[kt][0].w,
                        xa[kt][1].x, xa[kt][1].y, xa[kt][1].z, xa[kt][1].w };
        short8 ah, al;
        #pragma unroll
        for (int j = 0; j < 8; ++j) {
            float v = xf[j];
            unsigned short h = f2bf(v);
            ah[j] = (short)h;
            al[j] = (short)f2bf(v - bf2f(h));
        }
        #pragma unroll
        for (int ns = 0; ns < 4; ++ns) {
            short8 bh = *(const short8*)&sW[0][kt][ns][lane][0];
            short8 bl = *(const short8*)&sW[1][kt][ns][lane][0];
            acc[ns] = __builtin_amdgcn_mfma_f32_16x16x32_bf16(ah, bh, acc[ns], 0, 0, 0);
            acc[ns] = __builtin_amdgcn_mfma_f32_16x16x32_bf16(al, bh, acc[ns], 0, 0, 0);
            acc[ns] = __builtin_amdgcn_mfma_f32_16x16x32_bf16(ah, bl, acc[ns], 0, 0, 0);
        }
    }

    #pragma unroll
    for (int ns = 0; ns < 4; ++ns) {
        #pragma unroll
        for (int reg = 0; reg < 4; ++reg) {
            int r = row0 + q * 4 + reg;
            if (r < n)
                H[(size_t)r * CH + colh * 64 + ns * 16 + m] = f2bf(acc[ns][reg]);
        }
    }
}

// fused: blocks [0, nbE4): per-edge packed rank+degsum u64 atomic with
// XCD-LOCAL replica (rep = XCC_ID), grid-stride x4; blocks [nbE4,...): gemm1.
__global__ __launch_bounds__(TPB, 4)
void k_gemm_rank(const float* __restrict__ X, const short* __restrict__ Wsplit,
                 unsigned short* __restrict__ H, int n,
                 const int* __restrict__ dst, const float* __restrict__ ew,
                 u64* __restrict__ counts_rep, int* __restrict__ rank,
                 int E, int nbE4, int Np) {
    int bx = blockIdx.x;
    if (bx < nbE4) {
        const int rep = xcc_id();     // wave-uniform, XCD-local replica
        int stride = nbE4 * TPB;
        int e = bx * TPB + threadIdx.x;
        #pragma unroll
        for (int it = 0; it < 4; ++it, e += stride) {
            if (e < E) {
                int d = dst[e];
                if ((unsigned)d < (unsigned)n) {
                    u64 pk = (1ull << 40) |
                             (u64)(unsigned)__float2uint_rn(ew[e] * FIXS);
                    u64 old = atomicAdd(&counts_rep[(size_t)rep * Np + d], pk);
                    rank[e] = (rep << 28) | (int)(old >> 40);
                }
            }
        }
    } else {
        bx -= nbE4;
        int colh = bx & 1;
        gemm_body_f32(X, Wsplit + (size_t)colh * WIMG, H, n, bx >> 1, colh,
                      threadIdx.x);
    }
}

// ---------------------------------------------------------------------------
// scan1 (shfl): unpack 8 packed replicas -> v (true count) + dinv; scan the
// PADDED count vp=(v+7)&~7 for row_start; replica-exclusive offsets; last
// block top-scans padded partials into pp_s.
// ---------------------------------------------------------------------------
__global__ __launch_bounds__(SCANB)
void k_scan1(const u64* __restrict__ counts_rep, int Np,
             int* __restrict__ counts_tot, int* __restrict__ repoff8,
             int* __restrict__ row_start, float* __restrict__ dinv,
             int* __restrict__ partials, int* __restrict__ pp_s,
             int* __restrict__ done, int nb, int n) {
    __shared__ int swt[SCANB / 64];   // 16 wave totals / exclusive offsets
    __shared__ int slastS;
    const int tid  = threadIdx.x;
    const int lane = tid & 63;
    const int wid  = tid >> 6;
    const int gid  = blockIdx.x * SCANB + tid;

    int c[NREP];
    int v = 0;
    u64 wsum = 0;
    #pragma unroll
    for (int r = 0; r < NREP; ++r) {
        u64 pk = (gid < n) ? counts_rep[(size_t)r * Np + gid] : 0ull;
        c[r] = (int)(pk >> 40);
        wsum += pk & ((1ull << 40) - 1);
        v += c[r];
    }
    const int vp = (v + 7) & ~7;            // padded bucket length
    // wave-inclusive scan of padded counts
    int inc = vp;
    #pragma unroll
    for (int off = 1; off < 64; off <<= 1) {
        int t = __shfl_up(inc, off, 64);
        if (lane >= off) inc += t;
    }
    if (lane == 63) swt[wid] = inc;
    __syncthreads();
    if (wid == 0) {
        int wv_ = (lane < SCANB / 64) ? swt[lane] : 0;
        int winc = wv_;
        #pragma unroll
        for (int off = 1; off < SCANB / 64; off <<= 1) {
            int t = __shfl_up(winc, off, 64);
            if (lane >= off) winc += t;
        }
        if (lane < SCANB / 64) swt[lane] = winc - wv_;   // exclusive
    }
    __syncthreads();
    const int myincl = inc + swt[wid];      // block-inclusive padded prefix

    if (gid < n) {
        row_start[gid]  = myincl - vp;      // block-local exclusive (padded)
        counts_tot[gid] = v;                // true count
        dinv[gid] = rsqrtf(1.0f + (float)wsum * (1.0f / FIXS));
        int pre = 0;
        int ro[NREP];
        #pragma unroll
        for (int r = 0; r < NREP; ++r) { ro[r] = pre; pre += c[r]; }
        ((int4*)repoff8)[gid * 2 + 0] = make_int4(ro[0], ro[1], ro[2], ro[3]);
        ((int4*)repoff8)[gid * 2 + 1] = make_int4(ro[4], ro[5], ro[6], ro[7]);
    }
    if (tid == SCANB - 1) {                 // holds the block total
        partials[blockIdx.x] = myincl;
        __threadfence();
        int old = atomicAdd(done, 1);
        slastS = (old == nb - 1);
    }
    __syncthreads();
    if (slastS && tid < 64) {
        int pv = (tid < nb) ? atomicAdd(&partials[tid], 0) : 0;
        int i2 = pv;
        #pragma unroll
        for (int off = 1; off < 64; off <<= 1) {
            int t = __shfl_up(i2, off, 64);
            if ((tid & 63) >= off) i2 += t;
        }
        if (tid < nb) pp_s[tid] = i2 - pv;
    }
}

// fill: blocks [0,nbE): per-edge forward fill via rank (rep decoded from the
// rank word); blocks [nbE, nbE+nbN): per-node pad writer ({src=0,w=0} rounds
// buckets up to a multiple of 8). pp_s is valid here (scan completed).
__global__ void k_fill(const int* __restrict__ src, const int* __restrict__ dst,
                       const float* __restrict__ ew, const int* __restrict__ row_start,
                       const int* __restrict__ pp_s, const int* __restrict__ repoff8,
                       const int* __restrict__ rank, const float* __restrict__ dinv,
                       const int* __restrict__ counts_tot,
                       int2* __restrict__ edges, int E, int n, int nbE) {
    int bx = blockIdx.x;
    if (bx >= nbE) {
        int node = (bx - nbE) * TPB + threadIdx.x;
        if (node >= n) return;
        int v  = counts_tot[node];
        int vp = (v + 7) & ~7;
        if (v == vp) return;
        int base = row_start[node] + pp_s[node >> 10] + v;
        for (int k = 0; k < vp - v; ++k)
            edges[base + k] = make_int2(0, 0);   // w=0 pad, gathers row 0
        return;
    }
    int e = bx * TPB + threadIdx.x;
    if (e >= E) return;
    int s = src[e], d = dst[e];
    if ((unsigned)s >= (unsigned)n || (unsigned)d >= (unsigned)n) return;
    int rr   = rank[e];
    int rep  = (rr >> 28) & (NREP - 1);
    int slot = rr & 0x0FFFFFFF;
    int base = row_start[d] + pp_s[d >> 10] + repoff8[d * NREP + rep];
    edges[base + slot] = make_int2(s, __float_as_int(ew[e] * dinv[s]));
}

// ---------------------------------------------------------------------------
// aggregate core over UNscaled h (16 lanes/node, short8 loads). Buckets are
// padded to a multiple of 8 -> only full 8-wide batches, no tail.
//   o = di^2 * h[node] + di * sum_e w~_e * h[src_e] + bias
// ---------------------------------------------------------------------------
static __device__ __forceinline__ float8 agg_node8(
        const short8* __restrict__ h8, const int2* __restrict__ edges,
        float di, const float8 b, int node, int tx,
        const int* __restrict__ row_start, const int* __restrict__ pp_s,
        const int* __restrict__ counts) {
    float8 hv = bf8_to_f8(h8[(size_t)node * 16 + tx]);
    float8 acc;
    #pragma unroll
    for (int i = 0; i < 8; ++i) acc[i] = 0.f;

    int j   = row_start[node] + pp_s[node >> 10];
    int end = j + ((counts[node] + 7) & ~7);    // padded length

    for (; j < end; j += 8) {
        int2 e[8];
        #pragma unroll
        for (int i = 0; i < 8; ++i) e[i] = edges[j + i];
        short8 g[8];
        #pragma unroll
        for (int i = 0; i < 8; ++i) g[i] = h8[(size_t)e[i].x * 16 + tx];
        #pragma unroll
        for (int i = 0; i < 8; ++i) {
            float w = __int_as_float(e[i].y);
            float8 gf = bf8_to_f8(g[i]);
            #pragma unroll
            for (int c = 0; c < 8; ++c) acc[c] += gf[c] * w;
        }
    }

    float di2 = di * di;
    float8 o;
    #pragma unroll
    for (int c = 0; c < 8; ++c) o[c] = di2 * hv[c] + di * acc[c] + b[c];
    return o;
}

// ---------------------------------------------------------------------------
// k_agg_gemm: 16 nodes/block (agg1 parallel shape, 3125 blocks).
// Phase 1: one node-slice per thread -> LDS tile (pitch 17 short8, 4.3 KB).
// Phase 2: 16x128 tile @ W2; 4 waves split (colh, ns); 8 MFMAs/wave;
// B-frags from L2-hot global.
// ---------------------------------------------------------------------------
__global__ __launch_bounds__(TPB)
void k_agg_gemm(const unsigned short* __restrict__ h,
                const int* __restrict__ row_start, const int* __restrict__ pp_s,
                const int* __restrict__ counts, const int2* __restrict__ edges,
                const float* __restrict__ dinv, const float* __restrict__ bias,
                const short* __restrict__ W2img,   // Wsplit + 2*WIMG
                unsigned short* __restrict__ h2, int n) {
    __shared__ __align__(16) short8 tile[16 * 17];       // 4.3 KB, pitch 17
    const int tid = threadIdx.x;

    // ---- phase 1: aggregate 16 nodes, one slice per thread ----
    const int bnode0 = (int)blockIdx.x * 16;
    const int tx = tid & 15;
    const int tg = tid >> 4;          // node-local index [0,16)
    const int node = bnode0 + tg;
    float8 b;
    #pragma unroll
    for (int c = 0; c < 8; ++c) b[c] = bias[tx * 8 + c];
    short8 u;
    if (node < n) {
        float8 o = agg_node8((const short8*)h, edges, dinv[node], b, node,
                             tx, row_start, pp_s, counts);
        #pragma unroll
        for (int c = 0; c < 8; ++c) u[c] = (short)f2bf(fmaxf(o[c], 0.f));
    } else {
        #pragma unroll
        for (int c = 0; c < 8; ++c) u[c] = 0;
    }
    tile[tg * 17 + tx] = u;
    __syncthreads();

    // ---- phase 2: 16x128 tile @ 128x128 W2 (B from global, L2-hot) ----
    const int lane = tid & 63;
    const int wv   = tid >> 6;        // 0..3
    const int q    = lane >> 4;
    const int m    = lane & 15;
    const int ch   = wv & 1;
    const int ns0  = (wv >> 1) * 2;

    short8 a[4];
    #pragma unroll
    for (int kt = 0; kt < 4; ++kt)
        a[kt] = tile[m * 17 + kt * 4 + q];

    const short8* w2f = (const short8*)(W2img + (size_t)ch * WIMG);

    floatx4 acc[2];
    #pragma unroll
    for (int i = 0; i < 2; ++i) acc[i] = (floatx4){0.f, 0.f, 0.f, 0.f};

    #pragma unroll
    for (int kt = 0; kt < 4; ++kt) {
        #pragma unroll
        for (int i = 0; i < 2; ++i) {
            short8 bh = w2f[(kt * 4 + ns0 + i) * 64 + lane];
            acc[i] = __builtin_amdgcn_mfma_f32_16x16x32_bf16(a[kt], bh, acc[i],
                                                             0, 0, 0);
        }
    }

    #pragma unroll
    for (int i = 0; i < 2; ++i)
        #pragma unroll
        for (int reg = 0; reg < 4; ++reg) {
            int r = bnode0 + q * 4 + reg;
            if (r < n)
                h2[(size_t)r * CH + ch * 64 + (ns0 + i) * 16 + m] =
                    f2bf(acc[i][reg]);
        }
}

// agg2: out = relu(agg(h2)) in fp32.
__global__ __launch_bounds__(TPB)
void k_aggregate2(const unsigned short* __restrict__ h,
                  const int* __restrict__ row_start, const int* __restrict__ pp_s,
                  const int* __restrict__ counts, const int2* __restrict__ edges,
                  const float* __restrict__ dinv, const float* __restrict__ bias,
                  float* __restrict__ out, int n) {
    int t = blockIdx.x * blockDim.x + threadIdx.x;
    int node = t >> 4;
    if (node >= n) return;
    int tx = t & 15;
    float8 b;
    #pragma unroll
    for (int c = 0; c < 8; ++c) b[c] = bias[tx * 8 + c];
    float8 o = agg_node8((const short8*)h, edges, dinv[node], b, node, tx,
                         row_start, pp_s, counts);
    float4 lo = make_float4(fmaxf(o[0], 0.f), fmaxf(o[1], 0.f),
                            fmaxf(o[2], 0.f), fmaxf(o[3], 0.f));
    float4 hi = make_float4(fmaxf(o[4], 0.f), fmaxf(o[5], 0.f),
                            fmaxf(o[6], 0.f), fmaxf(o[7], 0.f));
    ((float4*)out)[(size_t)node * CH4 + tx * 2 + 0] = lo;
    ((float4*)out)[(size_t)node * CH4 + tx * 2 + 1] = hi;
}

// ---------------------------------------------------------------------------
extern "C" void kernel_launch(void* const* d_in, const int* in_sizes, int n_in,
                              void* d_out, int out_size, void* d_ws, size_t ws_size,
                              hipStream_t stream) {
    const float* x  = (const float*)d_in[0];   // [N,128]
    const int*   ei = (const int*)d_in[1];     // [2,E]
    const float* ew = (const float*)d_in[2];   // [E]
    const float* W1 = (const float*)d_in[3];
    const float* b1 = (const float*)d_in[4];
    const float* W2 = (const float*)d_in[5];
    const float* b2 = (const float*)d_in[6];
    float* out = (float*)d_out;                // [N,128]

    const int N = in_sizes[0] / CH;
    const int E = in_sizes[2];
    const int* src = ei;
    const int* dst = ei + E;

    // workspace layout (16B-aligned)
    size_t Np   = ((size_t)N + 255) & ~(size_t)255;
    size_t Ep   = ((size_t)E + 63) & ~(size_t)63;
    size_t Epad = (size_t)E + 8 * Np;          // padded edge capacity
    float* ws          = (float*)d_ws;
    float* dinv        = ws;                                // Np floats
    unsigned short* h  = (unsigned short*)(dinv + Np);      // N*CH bf16 (gemm1 out)
    unsigned short* h2 = h + (size_t)N * CH;                // N*CH bf16 (gemm2 out)
    // ---- contiguous zero region ----
    u64*   counts_rep  = (u64*)(h2 + (size_t)N * CH);       // NREP*Np u64 (packed)
    int*   done        = (int*)(counts_rep + NREP * Np);    // 64 ints (1 used)
    int    nzero4      = (int)((2 * NREP * Np + 64) / 4);
    // ---- rest ----
    int*  counts_tot   = done + 64;                         // Np ints
    int*  row_start    = counts_tot + Np;                   // Np ints
    int*  repoff8      = row_start + Np;                    // NREP*Np ints
    int*  rank         = repoff8 + NREP * Np;               // Ep ints
    int*  partials     = rank + Ep;                         // 64 ints
    int*  pp_s         = partials + 64;                     // 64 ints
    int2* edges        = (int2*)(pp_s + 64);                // Epad int2
    short* Wsplit      = (short*)(edges + Epad);            // 4*WIMG shorts

    const int nbE    = (E + TPB - 1) / TPB;
    const int nbN    = (N + TPB - 1) / TPB;
    const int nbE4   = (E + TPB * 4 - 1) / (TPB * 4);
    const int nbAgg  = (int)(((size_t)N * 16 + TPB - 1) / TPB);
    const int nbScan = (N + SCANB - 1) / SCANB;     // 49 <= 64
    const int nbGemm = 2 * ((N + 63) / 64);
    const int nbAG   = (N + 15) / 16;               // 16 nodes/block
    const int nbPrep = (2 * CH * CH + TPB - 1) / TPB;
    const int nbZero = (nzero4 + TPB - 1) / TPB;

    // ---- prep: split W + zero counters (fused) ----
    k_prep     <<<nbPrep + nbZero, TPB, 0, stream>>>(W1, W2, Wsplit,
                                                     (float4*)counts_rep,
                                                     nzero4, nbPrep);

    // ---- fused: XCD-local packed rank+degsum pass (grid-stride x4) | gemm1 ----
    k_gemm_rank<<<nbE4 + nbGemm, TPB, 0, stream>>>(x, Wsplit, h, N, dst, ew,
                                                   counts_rep, rank, E, nbE4,
                                                   (int)Np);
    // ---- CSR finalize (+ dinv), padded buckets ----
    k_scan1    <<<nbScan, SCANB, 0, stream>>>(counts_rep, (int)Np, counts_tot,
                                              repoff8, row_start, dinv,
                                              partials, pp_s, done, nbScan, N);
    // ---- forward fill + pad writer (fused grids) ----
    k_fill     <<<nbE + nbN, TPB, 0, stream>>>(src, dst, ew, row_start, pp_s,
                                               repoff8, rank, dinv, counts_tot,
                                               edges, E, N, nbE);

    // ---- layer 1 aggregate + layer 2 gemm (fused) -> h2 ----
    k_agg_gemm <<<nbAG, TPB, 0, stream>>>(h, row_start, pp_s, counts_tot,
                                          edges, dinv, b1,
                                          Wsplit + 2 * (size_t)WIMG, h2, N);
    // ---- layer 2 aggregate ----
    k_aggregate2<<<nbAgg, TPB, 0, stream>>>(h2, row_start, pp_s, counts_tot,
                                            edges, dinv, b2, out, N);
}